// Round 5
// baseline (222.034 us; speedup 1.0000x reference)
//
#include <hip/hip_runtime.h>
#include <math.h>

#define NE 8
#define KDIM 4096
#define PDIM 64
#define NQ 4                  // K split factor
#define QK (KDIM / NQ)        // 1024 floats per quarter
#define TPB 16                // tokens per block (4 per wave)
#define LROW (QK + 16)        // padded LDS row stride (floats), 16B-aligned
#define EPS_F32 1.1920929e-07f

typedef float f4 __attribute__((ext_vector_type(4)));

// Phase 1: partial logits. Block (group, q) handles 16 tokens x K-quarter q.
// - W quarter staged transposed into LDS once per block (only global W reads).
// - Each wave issues ALL 16 x-loads (NT) up front; vmem queue is pure x stream.
// - q==3 waves also fold in the 64 prompt dims (scattered W reads, tiny, L2-hot).
__global__ __launch_bounds__(256, 3)
void gate_partial(const float* __restrict__ x,
                  const float* __restrict__ prompt,
                  const float* __restrict__ W,
                  float* __restrict__ partials,   // [NQ][tokens][NE]
                  int tokens)
{
    const int tid   = threadIdx.x;
    const int lane  = tid & 63;
    const int wave  = tid >> 6;
    const int group = blockIdx.x >> 2;
    const int q     = blockIdx.x & 3;
    const int tbase = group * TPB + wave * 4;
    const int k0    = q * QK;

    __shared__ float lds_w[NE][LROW];   // 33,280 B

    // ---- issue all 16 x loads up front (streaming) ----
    f4 xv[4][4];
#pragma unroll
    for (int c = 0; c < 4; ++c)
#pragma unroll
        for (int t = 0; t < 4; ++t)
            xv[c][t] = __builtin_nontemporal_load(
                (const f4*)(x + (size_t)(tbase + t) * KDIM + k0 + c * 256 + lane * 4));

    // ---- stage W quarter transposed into LDS (coalesced global reads) ----
    // source region: rows [k0, k0+QK) x 8 = 8192 floats = 2048 f4, contiguous.
    const float* Wq = W + (size_t)k0 * NE;
#pragma unroll
    for (int it = 0; it < 8; ++it) {
        const int m  = it * 256 + tid;      // f4 index 0..2047
        const f4 v   = *(const f4*)(Wq + 4 * m);
        const int kl = m >> 1;              // local k
        const int e0 = (m & 1) * 4;         // expert half
        lds_w[e0 + 0][kl] = v.x;            // 2-way bank alias: free
        lds_w[e0 + 1][kl] = v.y;
        lds_w[e0 + 2][kl] = v.z;
        lds_w[e0 + 3][kl] = v.w;
    }
    __syncthreads();

    float acc[4][NE];
#pragma unroll
    for (int t = 0; t < 4; ++t)
#pragma unroll
        for (int e = 0; e < NE; ++e) acc[t][e] = 0.f;

    // ---- FMA: registers x LDS only ----
#pragma unroll
    for (int c = 0; c < 4; ++c) {
        f4 wv[NE];
#pragma unroll
        for (int e = 0; e < NE; ++e)
            wv[e] = *(const f4*)(&lds_w[e][c * 256 + lane * 4]);  // conflict-free b128
#pragma unroll
        for (int t = 0; t < 4; ++t)
#pragma unroll
            for (int e = 0; e < NE; ++e) {
                acc[t][e] = fmaf(xv[c][t].x, wv[e].x, acc[t][e]);
                acc[t][e] = fmaf(xv[c][t].y, wv[e].y, acc[t][e]);
                acc[t][e] = fmaf(xv[c][t].z, wv[e].z, acc[t][e]);
                acc[t][e] = fmaf(xv[c][t].w, wv[e].w, acc[t][e]);
            }
    }

    // ---- prompt (64 dims) folded into quarter 3 ----
    if (q == 3 && lane < 16) {
        const int k = lane * 4;
        f4 pv[4];
#pragma unroll
        for (int t = 0; t < 4; ++t)
            pv[t] = *(const f4*)(prompt + (size_t)(tbase + t) * PDIM + k);
        f4 wlo[4], whi[4];
#pragma unroll
        for (int j = 0; j < 4; ++j) {
            wlo[j] = *(const f4*)(W + (size_t)(KDIM + k + j) * NE);
            whi[j] = *(const f4*)(W + (size_t)(KDIM + k + j) * NE + 4);
        }
#pragma unroll
        for (int t = 0; t < 4; ++t) {
            const float* a = (const float*)&pv[t];
#pragma unroll
            for (int j = 0; j < 4; ++j) {
                acc[t][0] = fmaf(a[j], wlo[j].x, acc[t][0]);
                acc[t][1] = fmaf(a[j], wlo[j].y, acc[t][1]);
                acc[t][2] = fmaf(a[j], wlo[j].z, acc[t][2]);
                acc[t][3] = fmaf(a[j], wlo[j].w, acc[t][3]);
                acc[t][4] = fmaf(a[j], whi[j].x, acc[t][4]);
                acc[t][5] = fmaf(a[j], whi[j].y, acc[t][5]);
                acc[t][6] = fmaf(a[j], whi[j].z, acc[t][6]);
                acc[t][7] = fmaf(a[j], whi[j].w, acc[t][7]);
            }
        }
    }

    // ---- butterfly reduce across the wave ----
#pragma unroll
    for (int t = 0; t < 4; ++t)
#pragma unroll
        for (int e = 0; e < NE; ++e) {
            float v = acc[t][e];
#pragma unroll
            for (int off = 32; off >= 1; off >>= 1)
                v += __shfl_xor(v, off, 64);
            acc[t][e] = v;
        }

    // lanes 0..31 write this wave's 4x8 partials, coalesced
    if (lane < 32) {
        const int t4 = lane >> 3;
        const int e  = lane & 7;
        partials[((size_t)q * tokens + tbase + t4) * NE + e] = acc[t4][e];
    }
}

// Phase 2: combine quarters + bias, top-2, softmax, write masks & gates.
// Verified R1 lane mapping: lane = tt*16 + kk*8 + ee -> one mask element each.
__global__ __launch_bounds__(256)
void gate_epilogue(const float* __restrict__ partials,
                   const float* __restrict__ b,
                   float* __restrict__ out,
                   int tokens)
{
    const int tid   = threadIdx.x;
    const int lane  = tid & 63;
    const int wave  = tid >> 6;
    const int tbase = blockIdx.x * TPB + wave * 4;

    const int tt = lane >> 4;
    const int kk = (lane >> 3) & 1;
    const int ee = lane & 7;
    const int tg = tbase + tt;

    float lg[NE];
#pragma unroll
    for (int e = 0; e < NE; ++e) lg[e] = b[e];
#pragma unroll
    for (int qq = 0; qq < NQ; ++qq) {
        const f4 lo = *(const f4*)(partials + ((size_t)qq * tokens + tg) * NE);
        const f4 hi = *(const f4*)(partials + ((size_t)qq * tokens + tg) * NE + 4);
        lg[0] += lo.x; lg[1] += lo.y; lg[2] += lo.z; lg[3] += lo.w;
        lg[4] += hi.x; lg[5] += hi.y; lg[6] += hi.z; lg[7] += hi.w;
    }

    // top-2, strict > so smallest index wins ties (jax.lax.top_k semantics)
    float v0 = lg[0]; int i0 = 0;
#pragma unroll
    for (int e = 1; e < NE; ++e)
        if (lg[e] > v0) { v0 = lg[e]; i0 = e; }
    float v1 = (i0 == 0) ? lg[1] : lg[0];
    int   i1 = (i0 == 0) ? 1 : 0;
#pragma unroll
    for (int e = 0; e < NE; ++e)
        if (e != i0 && lg[e] > v1) { v1 = lg[e]; i1 = e; }

    float s = 0.f;
#pragma unroll
    for (int e = 0; e < NE; ++e) s += __expf(lg[e] - v0);
    const float g0 = 1.0f / s;
    const float g1 = __expf(v1 - v0) / s;
    const float denom = fmaxf(g0 + g1, EPS_F32);

    const int sel = kk ? i1 : i0;
    out[(size_t)tg * 16 + kk * 8 + ee] = (ee == sel) ? 1.0f : 0.0f;

    if ((lane & 15) < 2) {
        const float g = (ee == 0) ? (g0 / denom) : (g1 / denom);
        out[(size_t)tokens * 16 + (size_t)tg * 2 + ee] = g;
    }
}

extern "C" void kernel_launch(void* const* d_in, const int* in_sizes, int n_in,
                              void* d_out, int out_size, void* d_ws, size_t ws_size,
                              hipStream_t stream) {
    const float* x      = (const float*)d_in[0];
    const float* prompt = (const float*)d_in[1];
    const float* W      = (const float*)d_in[2];
    const float* b      = (const float*)d_in[3];
    float* out          = (float*)d_out;
    float* partials     = (float*)d_ws;           // NQ*tokens*NE*4 = 1 MB

    const int tokens = in_sizes[0] / KDIM;        // 8192

    hipLaunchKernelGGL(gate_partial, dim3((tokens / TPB) * NQ), dim3(256), 0, stream,
                       x, prompt, W, partials, tokens);
    hipLaunchKernelGGL(gate_epilogue, dim3(tokens / TPB), dim3(256), 0, stream,
                       partials, b, out, tokens);
}